// Round 12
// baseline (89.867 us; speedup 1.0000x reference)
//
#include <hip/hip_runtime.h>

#define NB 8
#define TAPS 5

typedef float f32x4 __attribute__((ext_vector_type(4)));

// generic post-vertical column antireflect remaps (length WIN)
template<int WIN>
__device__ __forceinline__ void remap_left(float A[WIN]) {
    const float o0 = A[0], o1 = A[1], o2 = A[2];
#pragma unroll
    for (int k = WIN - 1; k >= 2; --k) A[k] = A[k - 2];
    A[1] = 2.f * o0 - o1;
    A[0] = 2.f * o0 - o2;
}
template<int WIN>
__device__ __forceinline__ void remap_right(float A[WIN]) {
    const float e = A[WIN - 1], p1 = A[WIN - 2], p3 = A[WIN - 3];
#pragma unroll
    for (int k = 0; k < WIN - 2; ++k) A[k] = A[k + 2];
    A[WIN - 2] = 2.f * e - p1;
    A[WIN - 1] = 2.f * e - p3;
}

// Thread = (b, coarse-row pair n0=2g,n0+1, W coarse cols) -> 4 x 2W output patch.
// 6 input rows feed both output row-pairs; window = W+4 floats, all-float2 loads
// from an even clamped base (single code path). Row antireflect as data;
// column antireflect as post-vertical register remap. XCD-aware block swizzle.
template<int W, bool NTS>
__global__ __launch_bounds__(256)
void idwt_w(const float* __restrict__ Pss, const float* __restrict__ Psd,
            const float* __restrict__ Pds, const float* __restrict__ Pdd,
            const float* __restrict__ h, const float* __restrict__ g_,
            float* __restrict__ out, int N) {
    constexpr int WIN = W + 4;
    const int NJ = N / W;
    const int G2 = N >> 1;

    // XCD swizzle (grids are multiples of 8; guard anyway)
    const int nwg = gridDim.x;
    const int hw  = blockIdx.x;
    const int lb  = (nwg & 7) ? hw : ((hw & 7) * (nwg >> 3) + (hw >> 3));
    const int tid = lb * 256 + threadIdx.x;

    const int jc = tid % NJ;
    const int rest = tid / NJ;
    const int g = rest % G2;
    const int b = rest / G2;
    const int n0 = 2 * g;

    float hk0[TAPS], hk1[TAPS], gk0[TAPS], gk1[TAPS];   // uniform
#pragma unroll
    for (int t = 0; t < TAPS; ++t) {
        hk0[t] = h[8 - 2 * t];  hk1[t] = h[9 - 2 * t];
        gk0[t] = g_[8 - 2 * t]; gk1[t] = g_[9 - 2 * t];
    }

    const size_t plane = (size_t)N * N;
    const float* A  = Pss + (size_t)b * plane;
    const float* Bq = Psd + (size_t)b * plane;
    const float* C  = Pds + (size_t)b * plane;
    const float* D  = Pdd + (size_t)b * plane;

    // column window: logical cols jb..jb+WIN-1, physical base..base+WIN-1 (even)
    const int jb = W * jc - 2;
    int base = jb;
    if (base < 0) base = 0;
    if (base > N - WIN) base = N - WIN;

    float sA0[WIN], sA1[WIN], dA0[WIN], dA1[WIN];   // vertical acc for n0
    float sB0[WIN], sB1[WIN], dB0[WIN], dB1[WIN];   // vertical acc for n0+1
#pragma unroll
    for (int k = 0; k < WIN; ++k) {
        sA0[k] = sA1[k] = dA0[k] = dA1[k] = 0.f;
        sB0[k] = sB1[k] = dB0[k] = dB1[k] = 0.f;
    }

    // ---- vertical synthesis: 6 shared rows, row antireflect as data
#pragma unroll
    for (int r = 0; r < 6; ++r) {
        const int m = n0 - 2 + r;
        float wa[WIN], wb[WIN], wc[WIN], wd[WIN];
        if ((unsigned)m < (unsigned)N) {            // wave-uniform
            const float* pa = A  + (size_t)m * N + base;
            const float* pb = Bq + (size_t)m * N + base;
            const float* pc = C  + (size_t)m * N + base;
            const float* pd = D  + (size_t)m * N + base;
#pragma unroll
            for (int k = 0; k < WIN / 2; ++k) {
                float2 v;
                v = *reinterpret_cast<const float2*>(pa + 2 * k); wa[2*k] = v.x; wa[2*k+1] = v.y;
                v = *reinterpret_cast<const float2*>(pb + 2 * k); wb[2*k] = v.x; wb[2*k+1] = v.y;
                v = *reinterpret_cast<const float2*>(pc + 2 * k); wc[2*k] = v.x; wc[2*k+1] = v.y;
                v = *reinterpret_cast<const float2*>(pd + 2 * k); wd[2*k] = v.x; wd[2*k+1] = v.y;
            }
        } else {
            const int e  = (m < 0) ? 0 : N - 1;
            const int rr = (m < 0) ? -m : 2 * (N - 1) - m;
            const size_t oe  = (size_t)e * N + base;
            const size_t orf = (size_t)rr * N + base;
#pragma unroll
            for (int k = 0; k < WIN / 2; ++k) {
                float2 ev, rv;
                ev = *reinterpret_cast<const float2*>(A + oe + 2 * k);
                rv = *reinterpret_cast<const float2*>(A + orf + 2 * k);
                wa[2*k] = 2.f * ev.x - rv.x; wa[2*k+1] = 2.f * ev.y - rv.y;
                ev = *reinterpret_cast<const float2*>(Bq + oe + 2 * k);
                rv = *reinterpret_cast<const float2*>(Bq + orf + 2 * k);
                wb[2*k] = 2.f * ev.x - rv.x; wb[2*k+1] = 2.f * ev.y - rv.y;
                ev = *reinterpret_cast<const float2*>(C + oe + 2 * k);
                rv = *reinterpret_cast<const float2*>(C + orf + 2 * k);
                wc[2*k] = 2.f * ev.x - rv.x; wc[2*k+1] = 2.f * ev.y - rv.y;
                ev = *reinterpret_cast<const float2*>(D + oe + 2 * k);
                rv = *reinterpret_cast<const float2*>(D + orf + 2 * k);
                wd[2*k] = 2.f * ev.x - rv.x; wd[2*k+1] = 2.f * ev.y - rv.y;
            }
        }
        if (r < 5) {          // n0 uses taps t=r
#pragma unroll
            for (int k = 0; k < WIN; ++k) {
                sA0[k] += hk0[r] * wa[k] + gk0[r] * wb[k];
                sA1[k] += hk1[r] * wa[k] + gk1[r] * wb[k];
                dA0[k] += hk0[r] * wc[k] + gk0[r] * wd[k];
                dA1[k] += hk1[r] * wc[k] + gk1[r] * wd[k];
            }
        }
        if (r >= 1) {         // n0+1 uses taps t=r-1
            const int t = r - 1;
#pragma unroll
            for (int k = 0; k < WIN; ++k) {
                sB0[k] += hk0[t] * wa[k] + gk0[t] * wb[k];
                sB1[k] += hk1[t] * wa[k] + gk1[t] * wb[k];
                dB0[k] += hk0[t] * wc[k] + gk0[t] * wd[k];
                dB1[k] += hk1[t] * wc[k] + gk1[t] * wd[k];
            }
        }
    }

    // ---- column antireflect remap (edge strips only)
    if (jb < 0) {
        remap_left<WIN>(sA0); remap_left<WIN>(sA1); remap_left<WIN>(dA0); remap_left<WIN>(dA1);
        remap_left<WIN>(sB0); remap_left<WIN>(sB1); remap_left<WIN>(dB0); remap_left<WIN>(dB1);
    } else if (jb > base) {
        remap_right<WIN>(sA0); remap_right<WIN>(sA1); remap_right<WIN>(dA0); remap_right<WIN>(dA1);
        remap_right<WIN>(sB0); remap_right<WIN>(sB1); remap_right<WIN>(dB0); remap_right<WIN>(dB1);
    }

    // ---- horizontal synthesis + stores (4 output rows x 2W cols)
    const int M = 2 * N;
    float* dst = out + ((size_t)b * M + 4 * g) * M + 2 * W * jc;

    auto st4 = [&](float* p, float x, float y, float z, float w) {
        if constexpr (NTS) {
            f32x4 v = {x, y, z, w};
            __builtin_nontemporal_store(v, reinterpret_cast<f32x4*>(p));
        } else {
            *reinterpret_cast<float4*>(p) = make_float4(x, y, z, w);
        }
    };

#pragma unroll
    for (int pr = 0; pr < 2; ++pr) {   // row-pair: A (rows 4g,4g+1), B (rows 4g+2,4g+3)
        const float* s0 = pr ? sB0 : sA0;
        const float* s1 = pr ? sB1 : sA1;
        const float* d0 = pr ? dB0 : dA0;
        const float* d1 = pr ? dB1 : dA1;
        float oa[2 * W], ob[2 * W];
#pragma unroll
        for (int cc = 0; cc < W; ++cc) {
            float x0 = 0.f, x1 = 0.f, y0 = 0.f, y1 = 0.f;
#pragma unroll
            for (int t = 0; t < TAPS; ++t) {
                x0 += hk0[t] * s0[cc + t] + gk0[t] * d0[cc + t];
                x1 += hk1[t] * s0[cc + t] + gk1[t] * d0[cc + t];
                y0 += hk0[t] * s1[cc + t] + gk0[t] * d1[cc + t];
                y1 += hk1[t] * s1[cc + t] + gk1[t] * d1[cc + t];
            }
            oa[2 * cc] = x0; oa[2 * cc + 1] = x1;
            ob[2 * cc] = y0; ob[2 * cc + 1] = y1;
        }
        float* d0p = dst + (size_t)(2 * pr) * M;
        float* d1p = d0p + M;
#pragma unroll
        for (int k = 0; k < W / 2; ++k) {
            st4(d0p + 4 * k, oa[4*k], oa[4*k+1], oa[4*k+2], oa[4*k+3]);
            st4(d1p + 4 * k, ob[4*k], ob[4*k+1], ob[4*k+2], ob[4*k+3]);
        }
    }
}

extern "C" void kernel_launch(void* const* d_in, const int* in_sizes, int n_in,
                              void* d_out, int out_size, void* d_ws, size_t ws_size,
                              hipStream_t stream) {
    const float* ss = (const float*)d_in[0];
    const float* sd[3] = {(const float*)d_in[1], (const float*)d_in[2], (const float*)d_in[3]};
    const float* ds[3] = {(const float*)d_in[4], (const float*)d_in[5], (const float*)d_in[6]};
    const float* dd[3] = {(const float*)d_in[7], (const float*)d_in[8], (const float*)d_in[9]};
    const float* h = (const float*)d_in[10];
    const float* g = (const float*)d_in[11];
    float* out = (float*)d_out;

    char* ws = (char*)d_ws;
    float* I0 = (float*)ws;                        // level-2 output (2 MiB)
    float* I1 = (float*)(ws + ((size_t)2 << 20));  // level-1 output (8 MiB)

    // level 2: 128 -> 256 (W=4 keeps the tiny grid at 64 blocks)
    {
        const int N = 128;
        const int total = NB * (N >> 1) * (N / 4);
        idwt_w<4, false><<<(total + 255) / 256, 256, 0, stream>>>(
            ss, sd[2], ds[2], dd[2], h, g, I0, N);
    }
    // level 1: 256 -> 512 (W=8)
    {
        const int N = 256;
        const int total = NB * (N >> 1) * (N / 8);
        idwt_w<8, false><<<(total + 255) / 256, 256, 0, stream>>>(
            I0, sd[1], ds[1], dd[1], h, g, I1, N);
    }
    // level 0: 512 -> 1024 (W=8, nontemporal final stores)
    {
        const int N = 512;
        const int total = NB * (N >> 1) * (N / 8);
        idwt_w<8, true><<<(total + 255) / 256, 256, 0, stream>>>(
            I1, sd[0], ds[0], dd[0], h, g, out, N);
    }
}

// Round 13
// 74.243 us; speedup vs baseline: 1.2104x; 1.2104x over previous
//
#include <hip/hip_runtime.h>

#define NB 8
#define TAPS 5

typedef float f32x4 __attribute__((ext_vector_type(4)));

// Thread = (b, coarse row n, 8 coarse cols) -> 2x16 output patch.
// Lane loads ONLY its own 8 cols as 2 aligned float4 (wave loads 100% dense);
// the +-2 col halo of the vertical accumulators comes from __shfl (valid by
// linearity of the vertical synthesis). Wave-edge lanes are array edges at
// every level (NJ divides 64), where antireflect overrides the shfl garbage.
template<bool NTS>
__global__ __launch_bounds__(256)
void idwt_shfl(const float* __restrict__ Pss, const float* __restrict__ Psd,
               const float* __restrict__ Pds, const float* __restrict__ Pdd,
               const float* __restrict__ h, const float* __restrict__ g_,
               float* __restrict__ out, int N) {
    const int NJ = N >> 3;               // 8 coarse cols per thread
    const int nwg = gridDim.x;
    const int hw  = blockIdx.x;
    const int lb  = (nwg & 7) ? hw : ((hw & 7) * (nwg >> 3) + (hw >> 3));  // XCD swizzle
    const int tid = lb * 256 + threadIdx.x;

    const int jc = tid % NJ;
    const int rest = tid / NJ;
    const int n = rest % N;
    const int b = rest / N;

    float hk0[TAPS], hk1[TAPS], gk0[TAPS], gk1[TAPS];   // uniform -> scalarized
#pragma unroll
    for (int t = 0; t < TAPS; ++t) {
        hk0[t] = h[8 - 2 * t];  hk1[t] = h[9 - 2 * t];
        gk0[t] = g_[8 - 2 * t]; gk1[t] = g_[9 - 2 * t];
    }

    const size_t plane = (size_t)N * N;
    const float* A  = Pss + (size_t)b * plane;
    const float* Bq = Psd + (size_t)b * plane;
    const float* C  = Pds + (size_t)b * plane;
    const float* D  = Pdd + (size_t)b * plane;

    const int cb = 8 * jc;               // own cols [cb, cb+8), 32B-aligned

    float s0[8], s1[8], d0[8], d1[8];    // vertical accumulators (own cols only)
#pragma unroll
    for (int k = 0; k < 8; ++k) { s0[k] = s1[k] = d0[k] = d1[k] = 0.f; }

    // ---- vertical synthesis: 5 rows x 4 planes, 2 dense float4 loads each
#pragma unroll
    for (int r = 0; r < TAPS; ++r) {
        const int m = n - 2 + r;
        float wa[8], wb[8], wc[8], wd[8];
        if ((unsigned)m < (unsigned)N) {                 // wave-uniform (row-interior)
            const size_t o = (size_t)m * N + cb;
            *reinterpret_cast<float4*>(&wa[0]) = *reinterpret_cast<const float4*>(A + o);
            *reinterpret_cast<float4*>(&wa[4]) = *reinterpret_cast<const float4*>(A + o + 4);
            *reinterpret_cast<float4*>(&wb[0]) = *reinterpret_cast<const float4*>(Bq + o);
            *reinterpret_cast<float4*>(&wb[4]) = *reinterpret_cast<const float4*>(Bq + o + 4);
            *reinterpret_cast<float4*>(&wc[0]) = *reinterpret_cast<const float4*>(C + o);
            *reinterpret_cast<float4*>(&wc[4]) = *reinterpret_cast<const float4*>(C + o + 4);
            *reinterpret_cast<float4*>(&wd[0]) = *reinterpret_cast<const float4*>(D + o);
            *reinterpret_cast<float4*>(&wd[4]) = *reinterpret_cast<const float4*>(D + o + 4);
        } else {                                         // antireflect row as data
            const int e  = (m < 0) ? 0 : N - 1;
            const int rr = (m < 0) ? -m : 2 * (N - 1) - m;
            const size_t oe  = (size_t)e * N + cb;
            const size_t orf = (size_t)rr * N + cb;
            float ev[8], rv[8];
            *reinterpret_cast<float4*>(&ev[0]) = *reinterpret_cast<const float4*>(A + oe);
            *reinterpret_cast<float4*>(&ev[4]) = *reinterpret_cast<const float4*>(A + oe + 4);
            *reinterpret_cast<float4*>(&rv[0]) = *reinterpret_cast<const float4*>(A + orf);
            *reinterpret_cast<float4*>(&rv[4]) = *reinterpret_cast<const float4*>(A + orf + 4);
#pragma unroll
            for (int k = 0; k < 8; ++k) wa[k] = 2.f * ev[k] - rv[k];
            *reinterpret_cast<float4*>(&ev[0]) = *reinterpret_cast<const float4*>(Bq + oe);
            *reinterpret_cast<float4*>(&ev[4]) = *reinterpret_cast<const float4*>(Bq + oe + 4);
            *reinterpret_cast<float4*>(&rv[0]) = *reinterpret_cast<const float4*>(Bq + orf);
            *reinterpret_cast<float4*>(&rv[4]) = *reinterpret_cast<const float4*>(Bq + orf + 4);
#pragma unroll
            for (int k = 0; k < 8; ++k) wb[k] = 2.f * ev[k] - rv[k];
            *reinterpret_cast<float4*>(&ev[0]) = *reinterpret_cast<const float4*>(C + oe);
            *reinterpret_cast<float4*>(&ev[4]) = *reinterpret_cast<const float4*>(C + oe + 4);
            *reinterpret_cast<float4*>(&rv[0]) = *reinterpret_cast<const float4*>(C + orf);
            *reinterpret_cast<float4*>(&rv[4]) = *reinterpret_cast<const float4*>(C + orf + 4);
#pragma unroll
            for (int k = 0; k < 8; ++k) wc[k] = 2.f * ev[k] - rv[k];
            *reinterpret_cast<float4*>(&ev[0]) = *reinterpret_cast<const float4*>(D + oe);
            *reinterpret_cast<float4*>(&ev[4]) = *reinterpret_cast<const float4*>(D + oe + 4);
            *reinterpret_cast<float4*>(&rv[0]) = *reinterpret_cast<const float4*>(D + orf);
            *reinterpret_cast<float4*>(&rv[4]) = *reinterpret_cast<const float4*>(D + orf + 4);
#pragma unroll
            for (int k = 0; k < 8; ++k) wd[k] = 2.f * ev[k] - rv[k];
        }
#pragma unroll
        for (int k = 0; k < 8; ++k) {
            s0[k] += hk0[r] * wa[k] + gk0[r] * wb[k];
            s1[k] += hk1[r] * wa[k] + gk1[r] * wb[k];
            d0[k] += hk0[r] * wc[k] + gk0[r] * wd[k];
            d1[k] += hk1[r] * wc[k] + gk1[r] * wd[k];
        }
    }

    // ---- build 12-wide windows: halo via shfl, array-edge lanes via antireflect
    float ws0[12], ws1[12], wd0[12], wd1[12];
    auto mkwin = [&](const float* X, float* W) {
        float l0 = __shfl_up(X[6], 1);
        float l1 = __shfl_up(X[7], 1);
        float r0 = __shfl_down(X[0], 1);
        float r1 = __shfl_down(X[1], 1);
        if (jc == 0)      { l1 = 2.f * X[0] - X[1]; l0 = 2.f * X[0] - X[2]; }
        if (jc == NJ - 1) { r0 = 2.f * X[7] - X[6]; r1 = 2.f * X[7] - X[5]; }
        W[0] = l0; W[1] = l1;
#pragma unroll
        for (int k = 0; k < 8; ++k) W[k + 2] = X[k];
        W[10] = r0; W[11] = r1;
    };
    mkwin(s0, ws0); mkwin(s1, ws1); mkwin(d0, wd0); mkwin(d1, wd1);

    // ---- horizontal synthesis + stores (2 rows x 16 cols)
    const int M = 2 * N;
    float* dst = out + ((size_t)b * M + 2 * n) * M + 16 * jc;

    auto st4 = [&](float* p, const float* o) {
        if constexpr (NTS) {
            f32x4 v = {o[0], o[1], o[2], o[3]};
            __builtin_nontemporal_store(v, reinterpret_cast<f32x4*>(p));
        } else {
            *reinterpret_cast<float4*>(p) = make_float4(o[0], o[1], o[2], o[3]);
        }
    };

    {
        float o[16];
#pragma unroll
        for (int c = 0; c < 8; ++c) {
            float x0 = 0.f, x1 = 0.f;
#pragma unroll
            for (int t = 0; t < TAPS; ++t) {
                x0 += hk0[t] * ws0[c + t] + gk0[t] * wd0[c + t];
                x1 += hk1[t] * ws0[c + t] + gk1[t] * wd0[c + t];
            }
            o[2 * c] = x0; o[2 * c + 1] = x1;
        }
        st4(dst, o); st4(dst + 4, o + 4); st4(dst + 8, o + 8); st4(dst + 12, o + 12);
    }
    {
        float o[16];
#pragma unroll
        for (int c = 0; c < 8; ++c) {
            float x0 = 0.f, x1 = 0.f;
#pragma unroll
            for (int t = 0; t < TAPS; ++t) {
                x0 += hk0[t] * ws1[c + t] + gk0[t] * wd1[c + t];
                x1 += hk1[t] * ws1[c + t] + gk1[t] * wd1[c + t];
            }
            o[2 * c] = x0; o[2 * c + 1] = x1;
        }
        float* d1p = dst + M;
        st4(d1p, o); st4(d1p + 4, o + 4); st4(d1p + 8, o + 8); st4(d1p + 12, o + 12);
    }
}

extern "C" void kernel_launch(void* const* d_in, const int* in_sizes, int n_in,
                              void* d_out, int out_size, void* d_ws, size_t ws_size,
                              hipStream_t stream) {
    const float* ss = (const float*)d_in[0];
    const float* sd[3] = {(const float*)d_in[1], (const float*)d_in[2], (const float*)d_in[3]};
    const float* ds[3] = {(const float*)d_in[4], (const float*)d_in[5], (const float*)d_in[6]};
    const float* dd[3] = {(const float*)d_in[7], (const float*)d_in[8], (const float*)d_in[9]};
    const float* h = (const float*)d_in[10];
    const float* g = (const float*)d_in[11];
    float* out = (float*)d_out;

    char* ws = (char*)d_ws;
    float* I0 = (float*)ws;                        // level-2 output (2 MiB)
    float* I1 = (float*)(ws + ((size_t)2 << 20));  // level-1 output (8 MiB)

    // level 2: 128 -> 256   (8*128*16 = 16384 threads, 64 blocks)
    {
        const int N = 128;
        const int total = NB * N * (N >> 3);
        idwt_shfl<false><<<total / 256, 256, 0, stream>>>(ss, sd[2], ds[2], dd[2], h, g, I0, N);
    }
    // level 1: 256 -> 512   (65536 threads, 256 blocks)
    {
        const int N = 256;
        const int total = NB * N * (N >> 3);
        idwt_shfl<false><<<total / 256, 256, 0, stream>>>(I0, sd[1], ds[1], dd[1], h, g, I1, N);
    }
    // level 0: 512 -> 1024  (262144 threads, 1024 blocks; NT final stores)
    {
        const int N = 512;
        const int total = NB * N * (N >> 3);
        idwt_shfl<true><<<total / 256, 256, 0, stream>>>(I1, sd[0], ds[0], dd[0], h, g, out, N);
    }
}

// Round 14
// 41.669 us; speedup vs baseline: 2.1567x; 1.7817x over previous
//
#include <hip/hip_runtime.h>

#define NB 8
#define TAPS 5

// antireflect column fetch
__device__ __forceinline__ float ldc(const float* __restrict__ row, int j, int N) {
    if ((unsigned)j < (unsigned)N) return row[j];
    const int e  = (j < 0) ? 0 : (N - 1);
    const int rr = (j < 0) ? -j : (2 * (N - 1) - j);
    return 2.f * row[e] - row[rr];
}
// antireflect row+column fetch
__device__ __forceinline__ float ldrc(const float* __restrict__ plane, int m, int j, int N) {
    if ((unsigned)m < (unsigned)N) return ldc(plane + (size_t)m * N, j, N);
    const int e  = (m < 0) ? 0 : (N - 1);
    const int rm = (m < 0) ? -m : (2 * (N - 1) - m);
    return 2.f * ldc(plane + (size_t)e * N, j, N) - ldc(plane + (size_t)rm * N, j, N);
}
__device__ __forceinline__ void fma4(float4& a, float c, const float4& v) {
    a.x += c * v.x; a.y += c * v.y; a.z += c * v.z; a.w += c * v.w;
}
// async global->LDS, 16B per lane, no VGPR round trip
__device__ __forceinline__ void gl_lds16(const float* g, float* l) {
    __builtin_amdgcn_global_load_lds(
        (const __attribute__((address_space(1))) void*)g,
        (__attribute__((address_space(3))) void*)l, 16, 0, 0);
}

// Fused one-level 2D synthesis; staging via global_load_lds (width 16).
// Staged window: coarse cols j0=c0-4 .. +SW, rows m0=n0-2 .. +RH. 1D grid,
// XCD-swizzled. Phases 1/2 identical to the verified R5 kernel.
template<int TH, int TW>
__global__ __launch_bounds__(256)
void idwt_glds(const float* __restrict__ Ass, const float* __restrict__ Asd,
               const float* __restrict__ Ads, const float* __restrict__ Add,
               const float* __restrict__ h, const float* __restrict__ g,
               float* __restrict__ out, int N, int gx, int gy) {
    constexpr int THc = TH / 2;
    constexpr int SW  = TW / 2 + 8;      // multiple of 4
    constexpr int SW4 = SW / 4;
    constexpr int RH  = THc + 4;
    constexpr int NPP = RH * SW4;        // float4 per plane
    constexpr int NT  = 4 * NPP;         // float4 per tile
    constexpr int KMAX = (NT + 255) / 256;
    __shared__ float Ain[4][RH][SW];
    __shared__ float Sh[TH][SW];
    __shared__ float Dh[TH][SW];

    // XCD swizzle on 1D grid (all grids are multiples of 8; guard anyway)
    const int nwg = gridDim.x;
    const int hw  = blockIdx.x;
    const int lb  = (nwg & 7) ? hw : ((hw & 7) * (nwg >> 3) + (hw >> 3));
    const int strip = lb % gx;
    const int rowb  = (lb / gx) % gy;
    const int b     = lb / (gx * gy);

    const int r0 = rowb * TH;            // output row base
    const int w0 = strip * TW;           // output col base
    const int n0 = r0 >> 1, c0 = w0 >> 1;
    const int m0 = n0 - 2,  j0 = c0 - 4; // staged bases (16B-aligned cols)
    const int tid = threadIdx.x;

    float hk[2][TAPS], gk[2][TAPS];      // hk[p][t] = h[8-2t+p]
#pragma unroll
    for (int t = 0; t < TAPS; ++t) {
        hk[0][t] = h[8 - 2 * t]; hk[1][t] = h[9 - 2 * t];
        gk[0][t] = g[8 - 2 * t]; gk[1][t] = g[9 - 2 * t];
    }

    const size_t plane = (size_t)N * N;
    const float* P0 = Ass + (size_t)b * plane;
    const float* P1 = Asd + (size_t)b * plane;
    const float* P2 = Ads + (size_t)b * plane;
    const float* P3 = Add + (size_t)b * plane;

    float* lds0 = &Ain[0][0][0];

    // ---- phase 0: stage 4 planes into LDS
    const bool interior = (m0 >= 0) && (m0 + RH <= N) && (j0 >= 0) && (j0 + SW <= N);
    if (interior) {
#pragma unroll
        for (int k = 0; k < KMAX; ++k) {
            const int e = k * 256 + tid;
            if (e < NT) {
                const int q  = e / NPP;
                const int rm = e - q * NPP;
                const int r  = rm / SW4;
                const int fc = rm - r * SW4;
                const float* p = P0;
                if (q == 1) p = P1; else if (q == 2) p = P2; else if (q == 3) p = P3;
                gl_lds16(p + (size_t)(m0 + r) * N + j0 + 4 * fc, lds0 + 4 * e);
            }
        }
    } else {
        for (int e = tid; e < 4 * RH * SW; e += 256) {
            const int q  = e / (RH * SW);
            const int rm = e - q * (RH * SW);
            const int r  = rm / SW;
            const int kk = rm - r * SW;
            const float* p = P0;
            if (q == 1) p = P1; else if (q == 2) p = P2; else if (q == 3) p = P3;
            lds0[e] = ldrc(p, m0 + r, j0 + kk, N);
        }
    }
    __syncthreads();   // drains vmcnt (gload_lds completion) + lgkm

    // ---- phase 1: vertical synthesis, b128 LDS ops (verified in R5)
    for (int e = tid; e < THc * SW4; e += 256) {
        const int nl = e / SW4;
        const int fc = (e - nl * SW4) * 4;
        float4 s0 = {0,0,0,0}, s1 = {0,0,0,0}, d0 = {0,0,0,0}, d1 = {0,0,0,0};
#pragma unroll
        for (int t = 0; t < TAPS; ++t) {
            const float4 va = *reinterpret_cast<const float4*>(&Ain[0][nl + t][fc]);
            const float4 vb = *reinterpret_cast<const float4*>(&Ain[1][nl + t][fc]);
            const float4 vc = *reinterpret_cast<const float4*>(&Ain[2][nl + t][fc]);
            const float4 vd = *reinterpret_cast<const float4*>(&Ain[3][nl + t][fc]);
            fma4(s0, hk[0][t], va); fma4(s0, gk[0][t], vb);
            fma4(s1, hk[1][t], va); fma4(s1, gk[1][t], vb);
            fma4(d0, hk[0][t], vc); fma4(d0, gk[0][t], vd);
            fma4(d1, hk[1][t], vc); fma4(d1, gk[1][t], vd);
        }
        *reinterpret_cast<float4*>(&Sh[2 * nl][fc])     = s0;
        *reinterpret_cast<float4*>(&Sh[2 * nl + 1][fc]) = s1;
        *reinterpret_cast<float4*>(&Dh[2 * nl][fc])     = d0;
        *reinterpret_cast<float4*>(&Dh[2 * nl + 1][fc]) = d1;
    }
    __syncthreads();

    // ---- phase 2: horizontal synthesis + stores (verified in R5)
    const int M = 2 * N;
    constexpr int KW = TW / 8;
    for (int e = tid; e < TH * KW; e += 256) {
        const int r = e / KW;
        const int u = e - r * KW;
        float sv[12], dv[12];
        *reinterpret_cast<float4*>(&sv[0]) = *reinterpret_cast<const float4*>(&Sh[r][4 * u]);
        *reinterpret_cast<float4*>(&sv[4]) = *reinterpret_cast<const float4*>(&Sh[r][4 * u + 4]);
        *reinterpret_cast<float4*>(&sv[8]) = *reinterpret_cast<const float4*>(&Sh[r][4 * u + 8]);
        *reinterpret_cast<float4*>(&dv[0]) = *reinterpret_cast<const float4*>(&Dh[r][4 * u]);
        *reinterpret_cast<float4*>(&dv[4]) = *reinterpret_cast<const float4*>(&Dh[r][4 * u + 4]);
        *reinterpret_cast<float4*>(&dv[8]) = *reinterpret_cast<const float4*>(&Dh[r][4 * u + 8]);
        float o[8];
#pragma unroll
        for (int cc = 0; cc < 4; ++cc) {
            float o0 = 0.f, o1 = 0.f;
#pragma unroll
            for (int t = 0; t < TAPS; ++t) {
                const float sx = sv[cc + t + 2], dx = dv[cc + t + 2];
                o0 += hk[0][t] * sx + gk[0][t] * dx;
                o1 += hk[1][t] * sx + gk[1][t] * dx;
            }
            o[2 * cc] = o0; o[2 * cc + 1] = o1;
        }
        float* dst = out + ((size_t)b * M + (r0 + r)) * M + w0 + 8 * u;
        *reinterpret_cast<float4*>(dst)     = make_float4(o[0], o[1], o[2], o[3]);
        *reinterpret_cast<float4*>(dst + 4) = make_float4(o[4], o[5], o[6], o[7]);
    }
}

extern "C" void kernel_launch(void* const* d_in, const int* in_sizes, int n_in,
                              void* d_out, int out_size, void* d_ws, size_t ws_size,
                              hipStream_t stream) {
    const float* ss = (const float*)d_in[0];
    const float* sd[3] = {(const float*)d_in[1], (const float*)d_in[2], (const float*)d_in[3]};
    const float* ds[3] = {(const float*)d_in[4], (const float*)d_in[5], (const float*)d_in[6]};
    const float* dd[3] = {(const float*)d_in[7], (const float*)d_in[8], (const float*)d_in[9]};
    const float* h = (const float*)d_in[10];
    const float* g = (const float*)d_in[11];
    float* out = (float*)d_out;

    char* ws = (char*)d_ws;
    float* I0 = (float*)ws;                        // level-2 output (2 MiB)
    float* I1 = (float*)(ws + ((size_t)2 << 20));  // level-1 output (8 MiB)

    // level 2: 128 -> 256 (16x32 tiles, 1024 blocks)
    {
        const int N = 128, gx = 256 / 32, gy = 256 / 16;
        idwt_glds<16, 32><<<gx * gy * NB, 256, 0, stream>>>(
            ss, sd[2], ds[2], dd[2], h, g, I0, N, gx, gy);
    }
    // level 1: 256 -> 512 (32x64 tiles, 1024 blocks)
    {
        const int N = 256, gx = 512 / 64, gy = 512 / 32;
        idwt_glds<32, 64><<<gx * gy * NB, 256, 0, stream>>>(
            I0, sd[1], ds[1], dd[1], h, g, I1, N, gx, gy);
    }
    // level 0: 512 -> 1024 (32x64 tiles, 4096 blocks)
    {
        const int N = 512, gx = 1024 / 64, gy = 1024 / 32;
        idwt_glds<32, 64><<<gx * gy * NB, 256, 0, stream>>>(
            I1, sd[0], ds[0], dd[0], h, g, out, N, gx, gy);
    }
}